// Round 1
// baseline (583.826 us; speedup 1.0000x reference)
//
#include <hip/hip_runtime.h>
#include <hip/hip_bf16.h>
#include <cstdint>

#define B_BAGS 4096
#define L_LOOK 64
#define NT 4
#define V_ROWS 500000
#define D_EMB 128
#define FEAT 640

// ---------------------------------------------------------------------------
// Tiled fp32 GEMM: Y[M,N] = act(X[M,K] @ W[N,K]^T + bias[N])
// X row-major with leading dim ldx, W row-major [N,K], Y leading dim ldy.
// 256 threads, 16x16 thread grid, each thread TM x TN outputs.
// ---------------------------------------------------------------------------
template<int BM, int BN, int BK, int TM, int TN, bool RELU>
__global__ __launch_bounds__(256) void gemm_kernel(
    const float* __restrict__ X, int ldx,
    const float* __restrict__ W,
    const float* __restrict__ bias,
    float* __restrict__ Y, int ldy,
    int K)
{
    constexpr int PAD = 4;
    __shared__ float Xs[BK][BM + PAD];
    __shared__ float Ws[BK][BN + PAD];

    const int tid = threadIdx.x;
    const int tx = tid & 15;   // n direction
    const int ty = tid >> 4;   // m direction
    const int bm = blockIdx.y * BM;
    const int bn = blockIdx.x * BN;

    float acc[TM][TN];
#pragma unroll
    for (int i = 0; i < TM; ++i)
#pragma unroll
        for (int j = 0; j < TN; ++j) acc[i][j] = 0.f;

    constexpr int XT = BM * BK / 4;  // total float4 in X tile
    constexpr int WT = BN * BK / 4;

    for (int k0 = 0; k0 < K; k0 += BK) {
        __syncthreads();
        // stage X tile (transposed to k-major)
        for (int id = tid; id < XT; id += 256) {
            int m  = id >> 2;          // BK/4 == 4
            int k4 = id & 3;
            float4 v = *(const float4*)(X + (size_t)(bm + m) * ldx + k0 + k4 * 4);
            Xs[k4 * 4 + 0][m] = v.x;
            Xs[k4 * 4 + 1][m] = v.y;
            Xs[k4 * 4 + 2][m] = v.z;
            Xs[k4 * 4 + 3][m] = v.w;
        }
        // stage W tile (transposed to k-major)
        for (int id = tid; id < WT; id += 256) {
            int n  = id >> 2;
            int k4 = id & 3;
            float4 v = *(const float4*)(W + (size_t)(bn + n) * K + k0 + k4 * 4);
            Ws[k4 * 4 + 0][n] = v.x;
            Ws[k4 * 4 + 1][n] = v.y;
            Ws[k4 * 4 + 2][n] = v.z;
            Ws[k4 * 4 + 3][n] = v.w;
        }
        __syncthreads();

#pragma unroll
        for (int kk = 0; kk < BK; ++kk) {
            float a[TM], b[TN];
            if constexpr (TM % 4 == 0) {
#pragma unroll
                for (int i = 0; i < TM; i += 4)
                    *(float4*)&a[i] = *(const float4*)&Xs[kk][ty * TM + i];
            } else {
#pragma unroll
                for (int i = 0; i < TM; ++i) a[i] = Xs[kk][ty * TM + i];
            }
            if constexpr (TN % 4 == 0) {
#pragma unroll
                for (int j = 0; j < TN; j += 4)
                    *(float4*)&b[j] = *(const float4*)&Ws[kk][tx * TN + j];
            } else {
#pragma unroll
                for (int j = 0; j < TN; ++j) b[j] = Ws[kk][tx * TN + j];
            }
#pragma unroll
            for (int i = 0; i < TM; ++i)
#pragma unroll
                for (int j = 0; j < TN; ++j)
                    acc[i][j] += a[i] * b[j];
        }
    }

    // epilogue
#pragma unroll
    for (int i = 0; i < TM; ++i) {
        int m = bm + ty * TM + i;
#pragma unroll
        for (int j = 0; j < TN; j += 4) {
            int n = bn + tx * TN + j;
            float4 o;
            o.x = acc[i][j + 0] + bias[n + 0];
            o.y = acc[i][j + 1] + bias[n + 1];
            o.z = acc[i][j + 2] + bias[n + 2];
            o.w = acc[i][j + 3] + bias[n + 3];
            if (RELU) {
                o.x = fmaxf(o.x, 0.f);
                o.y = fmaxf(o.y, 0.f);
                o.z = fmaxf(o.z, 0.f);
                o.w = fmaxf(o.w, 0.f);
            }
            *(float4*)(Y + (size_t)m * ldy + n) = o;
        }
    }
}

// ---------------------------------------------------------------------------
// EmbeddingBag sum: one block per bag, wave w handles table w.
// Writes into feat[bag][128 + w*128 + d].
// ---------------------------------------------------------------------------
__global__ __launch_bounds__(256) void emb_kernel(
    const float* __restrict__ tables,   // [NT][V][D]
    const int*   __restrict__ idx,      // [B*L][NT]
    float*       __restrict__ feat)     // [B][FEAT]
{
    const int bag  = blockIdx.x;
    const int wave = threadIdx.x >> 6;   // table id
    const int lane = threadIdx.x & 63;

    const int my_idx = idx[((size_t)bag * L_LOOK + lane) * NT + wave];
    const float* tab = tables + (size_t)wave * V_ROWS * D_EMB;

    float2 acc = {0.f, 0.f};
#pragma unroll 8
    for (int j = 0; j < L_LOOK; ++j) {
        int r = __shfl(my_idx, j, 64);
        const float2* p = (const float2*)(tab + (size_t)r * D_EMB);
        float2 v = p[lane];
        acc.x += v.x;
        acc.y += v.y;
    }
    float* dst = feat + (size_t)bag * FEAT + D_EMB + wave * D_EMB;
    ((float2*)dst)[lane] = acc;
}

// ---------------------------------------------------------------------------
// Final layer: out[m] = sigmoid(dot(Z[m,:512], w) + b). One wave per row.
// ---------------------------------------------------------------------------
__global__ __launch_bounds__(256) void top2_kernel(
    const float* __restrict__ Z,    // [B,512]
    const float* __restrict__ w,    // [512]
    const float* __restrict__ bsc,  // [1]
    float*       __restrict__ out)  // [B]
{
    const int row  = blockIdx.x * 4 + (threadIdx.x >> 6);
    const int lane = threadIdx.x & 63;

    const float4* z  = (const float4*)(Z + (size_t)row * 512);
    const float4* wv = (const float4*)w;
    float4 a0 = z[lane],      w0 = wv[lane];
    float4 a1 = z[lane + 64], w1 = wv[lane + 64];
    float s = a0.x * w0.x + a0.y * w0.y + a0.z * w0.z + a0.w * w0.w
            + a1.x * w1.x + a1.y * w1.y + a1.z * w1.z + a1.w * w1.w;
#pragma unroll
    for (int off = 32; off > 0; off >>= 1) s += __shfl_down(s, off, 64);
    if (lane == 0) {
        float x = s + bsc[0];
        out[row] = 1.f / (1.f + expf(-x));
    }
}

// ---------------------------------------------------------------------------
extern "C" void kernel_launch(void* const* d_in, const int* in_sizes, int n_in,
                              void* d_out, int out_size, void* d_ws, size_t ws_size,
                              hipStream_t stream) {
    const float* x_dense = (const float*)d_in[0];   // [4096,512]
    const float* tables  = (const float*)d_in[1];   // [4,500000,128]
    const float* bw0 = (const float*)d_in[2];       // [1024,512]
    const float* bb0 = (const float*)d_in[3];
    const float* bw1 = (const float*)d_in[4];       // [512,1024]
    const float* bb1 = (const float*)d_in[5];
    const float* bw2 = (const float*)d_in[6];       // [128,512]
    const float* bb2 = (const float*)d_in[7];
    const float* tw0 = (const float*)d_in[8];       // [1024,640]
    const float* tb0 = (const float*)d_in[9];
    const float* tw1 = (const float*)d_in[10];      // [512,1024]
    const float* tb1 = (const float*)d_in[11];
    const float* tw2 = (const float*)d_in[12];      // [1,512]
    const float* tb2 = (const float*)d_in[13];
    const int*   x_idx = (const int*)d_in[14];      // [262144,4]
    float* out = (float*)d_out;                     // [4096]

    char* ws = (char*)d_ws;
    float* feat = (float*)(ws);                                  // [4096,640]
    float* h0   = (float*)(ws + (size_t)4096 * 640 * 4);         // [4096,1024]
    float* h1   = (float*)(ws + (size_t)4096 * 640 * 4
                              + (size_t)4096 * 1024 * 4);        // [4096,512]
    float* z0 = h0;   // reuse
    float* z1 = h1;   // reuse

    dim3 blk(256);

    // bottom MLP
    gemm_kernel<128,128,16,8,8,true><<<dim3(1024/128, 4096/128), blk, 0, stream>>>(
        x_dense, 512, bw0, bb0, h0, 1024, 512);
    gemm_kernel<64,128,16,4,8,true><<<dim3(512/128, 4096/64), blk, 0, stream>>>(
        h0, 1024, bw1, bb1, h1, 512, 1024);
    gemm_kernel<32,64,16,2,4,true><<<dim3(128/64, 4096/32), blk, 0, stream>>>(
        h1, 512, bw2, bb2, feat, 640, 512);   // writes feat[:, 0:128]

    // embedding bags -> feat[:, 128:640]
    emb_kernel<<<dim3(4096), blk, 0, stream>>>(tables, x_idx, feat);

    // top MLP
    gemm_kernel<128,128,16,8,8,true><<<dim3(1024/128, 4096/128), blk, 0, stream>>>(
        feat, 640, tw0, tb0, z0, 1024, 640);
    gemm_kernel<64,128,16,4,8,true><<<dim3(512/128, 4096/64), blk, 0, stream>>>(
        z0, 1024, tw1, tb1, z1, 512, 1024);
    top2_kernel<<<dim3(4096/4), blk, 0, stream>>>(z1, tw2, tb2, out);
}

// Round 2
// 361.021 us; speedup vs baseline: 1.6172x; 1.6172x over previous
//
#include <hip/hip_runtime.h>
#include <hip/hip_bf16.h>
#include <cstdint>

#define B_BAGS 4096
#define L_LOOK 64
#define NT 4
#define V_ROWS 500000
#define D_EMB 128
#define FEAT 640

typedef _Float16 half8 __attribute__((ext_vector_type(8)));
typedef _Float16 half4 __attribute__((ext_vector_type(4)));
typedef float f32x4 __attribute__((ext_vector_type(4)));

// ---------------------------------------------------------------------------
// fp16-MFMA GEMM: Y[M,N] = act(X[M,K] @ W[N,K]^T + bias[N]), fp32 in/out.
// X row-major ld=ldx, W row-major [N,K], Y row-major ld=ldy.
// 256 threads = 4 waves in 2x2 grid; each wave owns (BM/2)x(BN/2);
// fragments FM x FN of 16x16, K-step 64 (2 MFMA k-steps of 32).
// fp32 -> fp16 conversion happens during LDS staging.
// ---------------------------------------------------------------------------
template<int BM, int BN, bool RELU>
__global__ __launch_bounds__(256) void gemm_f16(
    const float* __restrict__ X, int ldx,
    const float* __restrict__ W,
    const float* __restrict__ bias,
    float* __restrict__ Y, int ldy,
    int K)
{
    constexpr int BK  = 64;
    constexpr int LDL = BK + 8;          // +8 halves pad = 16B -> 2-way banks (free)
    constexpr int FM  = BM / 32;
    constexpr int FN  = BN / 32;

    __shared__ _Float16 As[BM * LDL];
    __shared__ _Float16 Bs[BN * LDL];

    const int tid  = threadIdx.x;
    const int lane = tid & 63;
    const int wave = tid >> 6;
    const int wm   = wave >> 1;          // 0..1
    const int wn   = wave & 1;           // 0..1
    const int bm   = blockIdx.y * BM;
    const int bn   = blockIdx.x * BN;

    const int srow = tid >> 4;           // staging row 0..15
    const int sc4  = tid & 15;           // staging float4 col 0..15

    f32x4 acc[FM][FN] = {};

    for (int k0 = 0; k0 < K; k0 += BK) {
        __syncthreads();
        // stage A (convert fp32 -> fp16)
#pragma unroll
        for (int r = srow; r < BM; r += 16) {
            float4 v = *(const float4*)(X + (size_t)(bm + r) * ldx + k0 + sc4 * 4);
            half4 hv = { (_Float16)v.x, (_Float16)v.y, (_Float16)v.z, (_Float16)v.w };
            *(half4*)(As + r * LDL + sc4 * 4) = hv;
        }
        // stage B = W rows (same row-major-[*,K] pattern)
#pragma unroll
        for (int r = srow; r < BN; r += 16) {
            float4 v = *(const float4*)(W + (size_t)(bn + r) * K + k0 + sc4 * 4);
            half4 hv = { (_Float16)v.x, (_Float16)v.y, (_Float16)v.z, (_Float16)v.w };
            *(half4*)(Bs + r * LDL + sc4 * 4) = hv;
        }
        __syncthreads();

#pragma unroll
        for (int s = 0; s < 2; ++s) {
            const int kb = s * 32 + (lane >> 4) * 8;   // halves offset in row
            half8 a[FM], b[FN];
#pragma unroll
            for (int i = 0; i < FM; ++i)
                a[i] = *(const half8*)(As + (wm * (BM / 2) + i * 16 + (lane & 15)) * LDL + kb);
#pragma unroll
            for (int j = 0; j < FN; ++j)
                b[j] = *(const half8*)(Bs + (wn * (BN / 2) + j * 16 + (lane & 15)) * LDL + kb);
#pragma unroll
            for (int i = 0; i < FM; ++i)
#pragma unroll
                for (int j = 0; j < FN; ++j)
                    acc[i][j] = __builtin_amdgcn_mfma_f32_16x16x32_f16(
                        a[i], b[j], acc[i][j], 0, 0, 0);
        }
    }

    // epilogue: D[row = 4*(lane>>4)+e][col = lane&15] per fragment
#pragma unroll
    for (int i = 0; i < FM; ++i) {
        const int mbase = bm + wm * (BM / 2) + i * 16 + (lane >> 4) * 4;
#pragma unroll
        for (int j = 0; j < FN; ++j) {
            const int n = bn + wn * (BN / 2) + j * 16 + (lane & 15);
            const float bv = bias[n];
#pragma unroll
            for (int e = 0; e < 4; ++e) {
                float o = acc[i][j][e] + bv;
                if (RELU) o = fmaxf(o, 0.f);
                Y[(size_t)(mbase + e) * ldy + n] = o;
            }
        }
    }
}

// ---------------------------------------------------------------------------
// EmbeddingBag sum: one block per bag, wave w handles table w.
// Writes into feat[bag][128 + w*128 + d].
// ---------------------------------------------------------------------------
__global__ __launch_bounds__(256) void emb_kernel(
    const float* __restrict__ tables,   // [NT][V][D]
    const int*   __restrict__ idx,      // [B*L][NT]
    float*       __restrict__ feat)     // [B][FEAT]
{
    const int bag  = blockIdx.x;
    const int wave = threadIdx.x >> 6;   // table id
    const int lane = threadIdx.x & 63;

    const int my_idx = idx[((size_t)bag * L_LOOK + lane) * NT + wave];
    const float* tab = tables + (size_t)wave * V_ROWS * D_EMB;

    float2 acc = {0.f, 0.f};
#pragma unroll 8
    for (int j = 0; j < L_LOOK; ++j) {
        int r = __shfl(my_idx, j, 64);
        const float2* p = (const float2*)(tab + (size_t)r * D_EMB);
        float2 v = p[lane];
        acc.x += v.x;
        acc.y += v.y;
    }
    float* dst = feat + (size_t)bag * FEAT + D_EMB + wave * D_EMB;
    ((float2*)dst)[lane] = acc;
}

// ---------------------------------------------------------------------------
// Final layer: out[m] = sigmoid(dot(Z[m,:512], w) + b). One wave per row.
// ---------------------------------------------------------------------------
__global__ __launch_bounds__(256) void top2_kernel(
    const float* __restrict__ Z,    // [B,512]
    const float* __restrict__ w,    // [512]
    const float* __restrict__ bsc,  // [1]
    float*       __restrict__ out)  // [B]
{
    const int row  = blockIdx.x * 4 + (threadIdx.x >> 6);
    const int lane = threadIdx.x & 63;

    const float4* z  = (const float4*)(Z + (size_t)row * 512);
    const float4* wv = (const float4*)w;
    float4 a0 = z[lane],      w0 = wv[lane];
    float4 a1 = z[lane + 64], w1 = wv[lane + 64];
    float s = a0.x * w0.x + a0.y * w0.y + a0.z * w0.z + a0.w * w0.w
            + a1.x * w1.x + a1.y * w1.y + a1.z * w1.z + a1.w * w1.w;
#pragma unroll
    for (int off = 32; off > 0; off >>= 1) s += __shfl_down(s, off, 64);
    if (lane == 0) {
        float x = s + bsc[0];
        out[row] = 1.f / (1.f + expf(-x));
    }
}

// ---------------------------------------------------------------------------
extern "C" void kernel_launch(void* const* d_in, const int* in_sizes, int n_in,
                              void* d_out, int out_size, void* d_ws, size_t ws_size,
                              hipStream_t stream) {
    const float* x_dense = (const float*)d_in[0];   // [4096,512]
    const float* tables  = (const float*)d_in[1];   // [4,500000,128]
    const float* bw0 = (const float*)d_in[2];       // [1024,512]
    const float* bb0 = (const float*)d_in[3];
    const float* bw1 = (const float*)d_in[4];       // [512,1024]
    const float* bb1 = (const float*)d_in[5];
    const float* bw2 = (const float*)d_in[6];       // [128,512]
    const float* bb2 = (const float*)d_in[7];
    const float* tw0 = (const float*)d_in[8];       // [1024,640]
    const float* tb0 = (const float*)d_in[9];
    const float* tw1 = (const float*)d_in[10];      // [512,1024]
    const float* tb1 = (const float*)d_in[11];
    const float* tw2 = (const float*)d_in[12];      // [1,512]
    const float* tb2 = (const float*)d_in[13];
    const int*   x_idx = (const int*)d_in[14];      // [262144,4]
    float* out = (float*)d_out;                     // [4096]

    char* ws = (char*)d_ws;
    float* feat = (float*)(ws);                                  // [4096,640]
    float* h0   = (float*)(ws + (size_t)4096 * 640 * 4);         // [4096,1024]
    float* h1   = (float*)(ws + (size_t)4096 * 640 * 4
                              + (size_t)4096 * 1024 * 4);        // [4096,512]
    float* z0 = h0;   // reuse
    float* z1 = h1;   // reuse

    dim3 blk(256);

    // bottom MLP (fp16 MFMA)
    gemm_f16<128,128,true><<<dim3(1024/128, 4096/128), blk, 0, stream>>>(
        x_dense, 512, bw0, bb0, h0, 1024, 512);
    gemm_f16<128,128,true><<<dim3(512/128, 4096/128), blk, 0, stream>>>(
        h0, 1024, bw1, bb1, h1, 512, 1024);
    gemm_f16<64,64,true><<<dim3(128/64, 4096/64), blk, 0, stream>>>(
        h1, 512, bw2, bb2, feat, 640, 512);   // writes feat[:, 0:128]

    // embedding bags -> feat[:, 128:640]
    emb_kernel<<<dim3(4096), blk, 0, stream>>>(tables, x_idx, feat);

    // top MLP (fp16 MFMA)
    gemm_f16<128,128,true><<<dim3(1024/128, 4096/128), blk, 0, stream>>>(
        feat, 640, tw0, tb0, z0, 1024, 640);
    gemm_f16<128,128,true><<<dim3(512/128, 4096/128), blk, 0, stream>>>(
        z0, 1024, tw1, tb1, z1, 512, 1024);
    top2_kernel<<<dim3(4096/4), blk, 0, stream>>>(z1, tw2, tb2, out);
}

// Round 3
// 173.152 us; speedup vs baseline: 3.3718x; 2.0850x over previous
//
#include <hip/hip_runtime.h>
#include <hip/hip_bf16.h>
#include <cstdint>

#define B_BAGS 4096
#define L_LOOK 64
#define NT 4
#define V_ROWS 500000
#define D_EMB 128
#define FEAT 640

typedef _Float16 half8 __attribute__((ext_vector_type(8)));
typedef _Float16 half4 __attribute__((ext_vector_type(4)));
typedef float f32x4 __attribute__((ext_vector_type(4)));

#define GLOAD_LDS(g, l) __builtin_amdgcn_global_load_lds( \
    (const __attribute__((address_space(1))) void*)(g),   \
    (__attribute__((address_space(3))) void*)(l), 16, 0, 0)

// ---------------------------------------------------------------------------
// D0: fp32 -> fp16 conversion of x_dense + all weights (once per launch)
// ---------------------------------------------------------------------------
struct CvtArgs {
    const float* src[7];
    _Float16*    dst[7];
    int          n4[7];   // float4 count per tensor
};

__global__ __launch_bounds__(256) void cvt_kernel(CvtArgs a) {
    const int stride = gridDim.x * blockDim.x;
    const int t0 = blockIdx.x * blockDim.x + threadIdx.x;
#pragma unroll
    for (int t = 0; t < 7; ++t) {
        const float4* s = (const float4*)a.src[t];
        half4* d = (half4*)a.dst[t];
        for (int i = t0; i < a.n4[t]; i += stride) {
            float4 v = s[i];
            half4 h = { (_Float16)v.x, (_Float16)v.y, (_Float16)v.z, (_Float16)v.w };
            d[i] = h;
        }
    }
}

// ---------------------------------------------------------------------------
// fp16 GEMM body: Y[M,N] = act(X[M,K] @ W[N,K]^T + bias), all fp16 operands,
// fp32 bias/accum, fp16 output. m97 structure: global_load_lds width 16,
// single LDS buffer, 2 barriers/K-step, XOR-swizzled LDS (2-way = free).
// BK=64 halves (128 B rows, 8x 16B slots; swizzle slot ^= row&7).
// 4 waves in 2x2; wave tile (BM/2)x(BN/2); MFMA 16x16x32 f16.
// ---------------------------------------------------------------------------
template<int BM, int BN, bool RELU>
__device__ __forceinline__ void gemm_body(
    _Float16* lds,
    int bm, int bn,
    const _Float16* __restrict__ X, int ldx,
    const _Float16* __restrict__ W, int ldw,
    const float* __restrict__ bias,
    _Float16* __restrict__ Y, int ldy,
    int K)
{
    constexpr int BK = 64;                 // halves per row
    constexpr int FM = BM / 32;
    constexpr int FN = BN / 32;
    constexpr int AI = BM * 8 / 256;       // A: 16B-slot loads per thread
    constexpr int BI = BN * 8 / 256;

    _Float16* As = lds;                    // [BM][64] halves, swizzled
    _Float16* Bs = lds + BM * BK;          // [BN][64]

    const int tid  = threadIdx.x;
    const int lane = tid & 63;
    const int wave = tid >> 6;
    const int wm   = wave >> 1;
    const int wn   = wave & 1;
    const int q    = lane >> 4;            // 0..3
    const int r16  = lane & 15;

    f32x4 acc[FM][FN] = {};

    for (int k0 = 0; k0 < K; k0 += BK) {
        // stage A: thread covers linear 16B slot L; data slot is XOR-swizzled
#pragma unroll
        for (int i = 0; i < AI; ++i) {
            int L = i * 256 + tid;
            int row = L >> 3, sl = L & 7;
            const _Float16* src = X + (size_t)(bm + row) * ldx + k0 + ((sl ^ (row & 7)) * 8);
            GLOAD_LDS(src, As + (size_t)(i * 256 + wave * 64) * 8);
        }
#pragma unroll
        for (int j = 0; j < BI; ++j) {
            int L = j * 256 + tid;
            int row = L >> 3, sl = L & 7;
            const _Float16* src = W + (size_t)(bn + row) * ldw + k0 + ((sl ^ (row & 7)) * 8);
            GLOAD_LDS(src, Bs + (size_t)(j * 256 + wave * 64) * 8);
        }
        __syncthreads();   // drains vmcnt -> LDS tile ready

#pragma unroll
        for (int s = 0; s < 2; ++s) {      // two k=32 MFMA steps
            half8 a[FM], b[FN];
#pragma unroll
            for (int i = 0; i < FM; ++i) {
                int R = wm * (BM / 2) + i * 16 + r16;
                int sl = (s * 4 + q) ^ (R & 7);
                a[i] = *(const half8*)(As + R * BK + sl * 8);
            }
#pragma unroll
            for (int j = 0; j < FN; ++j) {
                int R = wn * (BN / 2) + j * 16 + r16;
                int sl = (s * 4 + q) ^ (R & 7);
                b[j] = *(const half8*)(Bs + R * BK + sl * 8);
            }
#pragma unroll
            for (int i = 0; i < FM; ++i)
#pragma unroll
                for (int j = 0; j < FN; ++j)
                    acc[i][j] = __builtin_amdgcn_mfma_f32_16x16x32_f16(
                        a[i], b[j], acc[i][j], 0, 0, 0);
        }
        __syncthreads();   // protect LDS before next stage
    }

    // epilogue: D[row = q*4+e][col = r16] per 16x16 fragment
#pragma unroll
    for (int i = 0; i < FM; ++i) {
        const int m0 = bm + wm * (BM / 2) + i * 16 + q * 4;
#pragma unroll
        for (int j = 0; j < FN; ++j) {
            const int n = bn + wn * (BN / 2) + j * 16 + r16;
            const float bv = bias[n];
#pragma unroll
            for (int e = 0; e < 4; ++e) {
                float o = acc[i][j][e] + bv;
                if (RELU) o = fmaxf(o, 0.f);
                Y[(size_t)(m0 + e) * ldy + n] = (_Float16)o;
            }
        }
    }
}

template<int BM, int BN, bool RELU>
__global__ __launch_bounds__(256) void gemm_h(
    const _Float16* __restrict__ X, int ldx,
    const _Float16* __restrict__ W, int ldw,
    const float* __restrict__ bias,
    _Float16* __restrict__ Y, int ldy,
    int K)
{
    __shared__ __align__(16) _Float16 lds[(BM + BN) * 64];
    gemm_body<BM, BN, RELU>(lds, blockIdx.y * BM, blockIdx.x * BN,
                            X, ldx, W, ldw, bias, Y, ldy, K);
}

// ---------------------------------------------------------------------------
// EmbeddingBag body: one block per bag; wave w = table w.
// float4/lane, 2 rows per wave instruction, fp32 accum, fp16 feat write.
// ---------------------------------------------------------------------------
__device__ __forceinline__ void emb_body(
    int bag,
    const float* __restrict__ tables,
    const int*   __restrict__ idx,
    _Float16*    __restrict__ feat)
{
    const int wave = threadIdx.x >> 6;
    const int lane = threadIdx.x & 63;
    const int l5   = lane >> 5;          // which of the 2 rows this instr
    const int c    = lane & 31;          // float4 slot within row

    const int my_idx = idx[((size_t)bag * L_LOOK + lane) * NT + wave];
    const float* tab = tables + (size_t)wave * V_ROWS * D_EMB;

    float4 acc = {0.f, 0.f, 0.f, 0.f};
#pragma unroll 16
    for (int j = 0; j < 32; ++j) {
        int r = __shfl(my_idx, 2 * j + l5, 64);
        float4 v = ((const float4*)(tab + (size_t)r * D_EMB))[c];
        acc.x += v.x; acc.y += v.y; acc.z += v.z; acc.w += v.w;
    }
    acc.x += __shfl_xor(acc.x, 32, 64);
    acc.y += __shfl_xor(acc.y, 32, 64);
    acc.z += __shfl_xor(acc.z, 32, 64);
    acc.w += __shfl_xor(acc.w, 32, 64);
    if (l5 == 0) {
        half4 h = { (_Float16)acc.x, (_Float16)acc.y, (_Float16)acc.z, (_Float16)acc.w };
        *(half4*)(feat + (size_t)bag * FEAT + D_EMB + wave * D_EMB + c * 4) = h;
    }
}

// D1: fused gemm1 (blocks 0..511) + embedding (blocks 512..4607).
__global__ __launch_bounds__(256) void fused_emb_gemm1(
    const _Float16* __restrict__ xh, const _Float16* __restrict__ bw0h,
    const float* __restrict__ bb0, _Float16* __restrict__ h0h,
    const float* __restrict__ tables, const int* __restrict__ idx,
    _Float16* __restrict__ feat)
{
    __shared__ __align__(16) _Float16 lds[(64 + 128) * 64];
    const int bid = blockIdx.x;
    if (bid < 512) {
        const int bn = (bid >> 6) * 128;   // 8 n-tiles
        const int bm = (bid & 63) * 64;    // 64 m-tiles
        gemm_body<64, 128, true>(lds, bm, bn, xh, 512, bw0h, 512, bb0, h0h, 1024, 512);
    } else {
        emb_body(bid - 512, tables, idx, feat);
    }
}

// ---------------------------------------------------------------------------
// Final layer: out[m] = sigmoid(dot(z1[m,:512], w) + b), fp16 inputs.
// ---------------------------------------------------------------------------
__global__ __launch_bounds__(256) void top2_h(
    const _Float16* __restrict__ Z,
    const _Float16* __restrict__ w,
    const float* __restrict__ bsc,
    float* __restrict__ out)
{
    const int row  = blockIdx.x * 4 + (threadIdx.x >> 6);
    const int lane = threadIdx.x & 63;

    half8 z  = *(const half8*)(Z + (size_t)row * 512 + lane * 8);
    half8 wv = *(const half8*)(w + lane * 8);
    float s = 0.f;
#pragma unroll
    for (int i = 0; i < 8; ++i) s += (float)z[i] * (float)wv[i];
#pragma unroll
    for (int off = 32; off > 0; off >>= 1) s += __shfl_down(s, off, 64);
    if (lane == 0) {
        float x = s + bsc[0];
        out[row] = 1.f / (1.f + expf(-x));
    }
}

// ---------------------------------------------------------------------------
extern "C" void kernel_launch(void* const* d_in, const int* in_sizes, int n_in,
                              void* d_out, int out_size, void* d_ws, size_t ws_size,
                              hipStream_t stream) {
    const float* x_dense = (const float*)d_in[0];   // [4096,512]
    const float* tables  = (const float*)d_in[1];   // [4,500000,128]
    const float* bw0 = (const float*)d_in[2];       // [1024,512]
    const float* bb0 = (const float*)d_in[3];
    const float* bw1 = (const float*)d_in[4];       // [512,1024]
    const float* bb1 = (const float*)d_in[5];
    const float* bw2 = (const float*)d_in[6];       // [128,512]
    const float* bb2 = (const float*)d_in[7];
    const float* tw0 = (const float*)d_in[8];       // [1024,640]
    const float* tb0 = (const float*)d_in[9];
    const float* tw1 = (const float*)d_in[10];      // [512,1024]
    const float* tb1 = (const float*)d_in[11];
    const float* tw2 = (const float*)d_in[12];      // [1,512]
    const float* tb2 = (const float*)d_in[13];
    const int*   x_idx = (const int*)d_in[14];      // [262144,4]
    float* out = (float*)d_out;                     // [4096]

    char* p = (char*)d_ws;
    auto alloc = [&](size_t bytes) {
        char* r = p; p += (bytes + 255) & ~(size_t)255; return r;
    };
    _Float16* xh   = (_Float16*)alloc((size_t)4096 * 512 * 2);
    _Float16* bw0h = (_Float16*)alloc((size_t)1024 * 512 * 2);
    _Float16* bw1h = (_Float16*)alloc((size_t)512 * 1024 * 2);
    _Float16* bw2h = (_Float16*)alloc((size_t)128 * 512 * 2);
    _Float16* tw0h = (_Float16*)alloc((size_t)1024 * 640 * 2);
    _Float16* tw1h = (_Float16*)alloc((size_t)512 * 1024 * 2);
    _Float16* tw2h = (_Float16*)alloc((size_t)512 * 2);
    _Float16* h0h  = (_Float16*)alloc((size_t)4096 * 1024 * 2);
    _Float16* h1h  = (_Float16*)alloc((size_t)4096 * 512 * 2);
    _Float16* feat = (_Float16*)alloc((size_t)4096 * 640 * 2);
    _Float16* z0h  = (_Float16*)alloc((size_t)4096 * 1024 * 2);
    _Float16* z1h  = (_Float16*)alloc((size_t)4096 * 512 * 2);

    CvtArgs ca;
    ca.src[0] = x_dense; ca.dst[0] = xh;   ca.n4[0] = 4096 * 512 / 4;
    ca.src[1] = bw0;     ca.dst[1] = bw0h; ca.n4[1] = 1024 * 512 / 4;
    ca.src[2] = bw1;     ca.dst[2] = bw1h; ca.n4[2] = 512 * 1024 / 4;
    ca.src[3] = bw2;     ca.dst[3] = bw2h; ca.n4[3] = 128 * 512 / 4;
    ca.src[4] = tw0;     ca.dst[4] = tw0h; ca.n4[4] = 1024 * 640 / 4;
    ca.src[5] = tw1;     ca.dst[5] = tw1h; ca.n4[5] = 512 * 1024 / 4;
    ca.src[6] = tw2;     ca.dst[6] = tw2h; ca.n4[6] = 512 / 4;

    dim3 blk(256);

    // D0: convert x_dense + weights to fp16
    cvt_kernel<<<dim3(1024), blk, 0, stream>>>(ca);

    // D1: gemm1 (512 blocks, scheduled first) + embedding (4096 blocks)
    fused_emb_gemm1<<<dim3(512 + B_BAGS), blk, 0, stream>>>(
        xh, bw0h, bb0, h0h, tables, x_idx, feat);

    // D2: h0h @ bw1h^T -> h1h [4096,512]
    gemm_h<64, 128, true><<<dim3(4, 64), blk, 0, stream>>>(
        h0h, 1024, bw1h, 1024, bb1, h1h, 512, 1024);

    // D3: h1h @ bw2h^T -> feat[:, 0:128] (ldy=640)
    gemm_h<64, 128, true><<<dim3(1, 64), blk, 0, stream>>>(
        h1h, 512, bw2h, 512, bb2, feat, 640, 512);

    // D4: feat @ tw0h^T -> z0h [4096,1024]
    gemm_h<64, 128, true><<<dim3(8, 64), blk, 0, stream>>>(
        feat, 640, tw0h, 640, tb0, z0h, 1024, 640);

    // D5: z0h @ tw1h^T -> z1h [4096,512]
    gemm_h<64, 128, true><<<dim3(4, 64), blk, 0, stream>>>(
        z0h, 1024, tw1h, 1024, tb1, z1h, 512, 1024);

    // D6: sigmoid(z1h . tw2h + tb2)
    top2_h<<<dim3(1024), blk, 0, stream>>>(z1h, tw2h, tb2, out);
}

// Round 5
// 166.669 us; speedup vs baseline: 3.5029x; 1.0389x over previous
//
#include <hip/hip_runtime.h>
#include <hip/hip_bf16.h>
#include <cstdint>

#define B_BAGS 4096
#define L_LOOK 64
#define NT 4
#define V_ROWS 500000
#define D_EMB 128
#define FEAT 640

typedef _Float16 half8 __attribute__((ext_vector_type(8)));
typedef _Float16 half4 __attribute__((ext_vector_type(4)));
typedef float f32x4 __attribute__((ext_vector_type(4)));

#define GLOAD_LDS(g, l) __builtin_amdgcn_global_load_lds( \
    (const __attribute__((address_space(1))) void*)(g),   \
    (__attribute__((address_space(3))) void*)(l), 16, 0, 0)

// ---------------------------------------------------------------------------
// fp16 GEMM body: Y[M,N] = act(X[M,K] @ W[N,K]^T + bias), fp16 operands,
// fp32 accum, fp16 out. global_load_lds width 16, XOR-swizzled LDS.
// 4 waves in 2x2; wave tile (BM/2)x(BN/2); MFMA 16x16x32 f16.
// ---------------------------------------------------------------------------
template<int BM, int BN, bool RELU>
__device__ __forceinline__ void gemm_body(
    _Float16* lds,
    int bm, int bn,
    const _Float16* __restrict__ X, int ldx,
    const _Float16* __restrict__ W, int ldw,
    const float* __restrict__ bias,
    _Float16* __restrict__ Y, int ldy,
    int K)
{
    constexpr int BK = 64;                 // halves per row
    constexpr int FM = BM / 32;
    constexpr int FN = BN / 32;
    constexpr int AI = BM * 8 / 256;
    constexpr int BI = BN * 8 / 256;

    _Float16* As = lds;                    // [BM][64] halves, swizzled
    _Float16* Bs = lds + BM * BK;          // [BN][64]

    const int tid  = threadIdx.x;
    const int lane = tid & 63;
    const int wave = tid >> 6;
    const int wm   = wave >> 1;
    const int wn   = wave & 1;
    const int q    = lane >> 4;
    const int r16  = lane & 15;

    f32x4 acc[FM][FN] = {};

    for (int k0 = 0; k0 < K; k0 += BK) {
#pragma unroll
        for (int i = 0; i < AI; ++i) {
            int L = i * 256 + tid;
            int row = L >> 3, sl = L & 7;
            const _Float16* src = X + (size_t)(bm + row) * ldx + k0 + ((sl ^ (row & 7)) * 8);
            GLOAD_LDS(src, As + (size_t)(i * 256 + wave * 64) * 8);
        }
#pragma unroll
        for (int j = 0; j < BI; ++j) {
            int L = j * 256 + tid;
            int row = L >> 3, sl = L & 7;
            const _Float16* src = W + (size_t)(bn + row) * ldw + k0 + ((sl ^ (row & 7)) * 8);
            GLOAD_LDS(src, Bs + (size_t)(j * 256 + wave * 64) * 8);
        }
        __syncthreads();

#pragma unroll
        for (int s = 0; s < 2; ++s) {
            half8 a[FM], b[FN];
#pragma unroll
            for (int i = 0; i < FM; ++i) {
                int R = wm * (BM / 2) + i * 16 + r16;
                int sl = (s * 4 + q) ^ (R & 7);
                a[i] = *(const half8*)(As + R * BK + sl * 8);
            }
#pragma unroll
            for (int j = 0; j < FN; ++j) {
                int R = wn * (BN / 2) + j * 16 + r16;
                int sl = (s * 4 + q) ^ (R & 7);
                b[j] = *(const half8*)(Bs + R * BK + sl * 8);
            }
#pragma unroll
            for (int i = 0; i < FM; ++i)
#pragma unroll
                for (int j = 0; j < FN; ++j)
                    acc[i][j] = __builtin_amdgcn_mfma_f32_16x16x32_f16(
                        a[i], b[j], acc[i][j], 0, 0, 0);
        }
        __syncthreads();
    }

#pragma unroll
    for (int i = 0; i < FM; ++i) {
        const int m0 = bm + wm * (BM / 2) + i * 16 + q * 4;
#pragma unroll
        for (int j = 0; j < FN; ++j) {
            const int n = bn + wn * (BN / 2) + j * 16 + r16;
            const float bv = bias[n];
#pragma unroll
            for (int e = 0; e < 4; ++e) {
                float o = acc[i][j][e] + bv;
                if (RELU) o = fmaxf(o, 0.f);
                Y[(size_t)(m0 + e) * ldy + n] = (_Float16)o;
            }
        }
    }
}

template<int BM, int BN, bool RELU>
__global__ __launch_bounds__(256, 3) void gemm_h(
    const _Float16* __restrict__ X, int ldx,
    const _Float16* __restrict__ W, int ldw,
    const float* __restrict__ bias,
    _Float16* __restrict__ Y, int ldy,
    int K)
{
    __shared__ __align__(16) _Float16 lds[(BM + BN) * 64];
    gemm_body<BM, BN, RELU>(lds, blockIdx.y * BM, blockIdx.x * BN,
                            X, ldx, W, ldw, bias, Y, ldy, K);
}

// ---------------------------------------------------------------------------
// EmbeddingBag body: wave w = table w; float4/lane, 2 rows per instruction.
// ---------------------------------------------------------------------------
__device__ __forceinline__ void emb_body(
    int bag,
    const float* __restrict__ tables,
    const int*   __restrict__ idx,
    _Float16*    __restrict__ feat)
{
    const int wave = threadIdx.x >> 6;
    const int lane = threadIdx.x & 63;
    const int l5   = lane >> 5;
    const int c    = lane & 31;

    const int my_idx = idx[((size_t)bag * L_LOOK + lane) * NT + wave];
    const float* tab = tables + (size_t)wave * V_ROWS * D_EMB;

    float4 acc = {0.f, 0.f, 0.f, 0.f};
#pragma unroll 16
    for (int j = 0; j < 32; ++j) {
        int r = __shfl(my_idx, 2 * j + l5, 64);
        float4 v = ((const float4*)(tab + (size_t)r * D_EMB))[c];
        acc.x += v.x; acc.y += v.y; acc.z += v.z; acc.w += v.w;
    }
    acc.x += __shfl_xor(acc.x, 32, 64);
    acc.y += __shfl_xor(acc.y, 32, 64);
    acc.z += __shfl_xor(acc.z, 32, 64);
    acc.w += __shfl_xor(acc.w, 32, 64);
    if (l5 == 0) {
        half4 h = { (_Float16)acc.x, (_Float16)acc.y, (_Float16)acc.z, (_Float16)acc.w };
        *(half4*)(feat + (size_t)bag * FEAT + D_EMB + wave * D_EMB + c * 4) = h;
    }
}

// ---------------------------------------------------------------------------
// Fused dispatch: [0,G) gemm tiles, [G,G+C) cvt blocks, rest embedding bags.
// All roles independent within the dispatch (no intra-dispatch data deps).
// ---------------------------------------------------------------------------
struct CvtRest {
    const float* src[5];
    _Float16*    dst[5];
    int          n4[5];
};

template<int BM, int BN, bool RELU>
__global__ __launch_bounds__(256, 3) void fused_gemm_emb(
    const _Float16* __restrict__ X, int ldx,
    const _Float16* __restrict__ W, int ldw,
    const float* __restrict__ bias,
    _Float16* __restrict__ Y, int ldy, int K,
    int gemmBlocks, int mTiles,
    int cvtBlocks, CvtRest cvt,
    int embBase,
    const float* __restrict__ tables,
    const int*   __restrict__ idx,
    _Float16*    __restrict__ feat)
{
    __shared__ __align__(16) _Float16 lds[(BM + BN) * 64];
    const int bid = blockIdx.x;
    if (bid < gemmBlocks) {
        const int bm = (bid % mTiles) * BM;
        const int bn = (bid / mTiles) * BN;
        gemm_body<BM, BN, RELU>(lds, bm, bn, X, ldx, W, ldw, bias, Y, ldy, K);
    } else if (bid < gemmBlocks + cvtBlocks) {
        const int t0 = (bid - gemmBlocks) * 256 + threadIdx.x;
        const int stride = cvtBlocks * 256;
#pragma unroll
        for (int t = 0; t < 5; ++t) {
            const float4* s = (const float4*)cvt.src[t];
            half4* d = (half4*)cvt.dst[t];
            for (int i = t0; i < cvt.n4[t]; i += stride) {
                float4 v = s[i];
                half4 h = { (_Float16)v.x, (_Float16)v.y, (_Float16)v.z, (_Float16)v.w };
                d[i] = h;
            }
        }
    } else {
        emb_body(embBase + (bid - gemmBlocks - cvtBlocks), tables, idx, feat);
    }
}

// ---------------------------------------------------------------------------
// D0: cvt of xh + bw0h only (needed by D1's gemm1)
// ---------------------------------------------------------------------------
__global__ __launch_bounds__(256) void cvt2_kernel(
    const float* __restrict__ s0, _Float16* __restrict__ d0, int n0,
    const float* __restrict__ s1, _Float16* __restrict__ d1, int n1)
{
    const int stride = gridDim.x * blockDim.x;
    const int t0 = blockIdx.x * blockDim.x + threadIdx.x;
    for (int i = t0; i < n0; i += stride) {
        float4 v = ((const float4*)s0)[i];
        half4 h = { (_Float16)v.x, (_Float16)v.y, (_Float16)v.z, (_Float16)v.w };
        ((half4*)d0)[i] = h;
    }
    for (int i = t0; i < n1; i += stride) {
        float4 v = ((const float4*)s1)[i];
        half4 h = { (_Float16)v.x, (_Float16)v.y, (_Float16)v.z, (_Float16)v.w };
        ((half4*)d1)[i] = h;
    }
}

// ---------------------------------------------------------------------------
// Final layer: out[m] = sigmoid(dot(z1[m,:512], w) + b), fp16 inputs.
// ---------------------------------------------------------------------------
__global__ __launch_bounds__(256) void top2_h(
    const _Float16* __restrict__ Z,
    const _Float16* __restrict__ w,
    const float* __restrict__ bsc,
    float* __restrict__ out)
{
    const int row  = blockIdx.x * 4 + (threadIdx.x >> 6);
    const int lane = threadIdx.x & 63;

    half8 z  = *(const half8*)(Z + (size_t)row * 512 + lane * 8);
    half8 wv = *(const half8*)(w + lane * 8);
    float s = 0.f;
#pragma unroll
    for (int i = 0; i < 8; ++i) s += (float)z[i] * (float)wv[i];
#pragma unroll
    for (int off = 32; off > 0; off >>= 1) s += __shfl_down(s, off, 64);
    if (lane == 0) {
        float x = s + bsc[0];
        out[row] = 1.f / (1.f + expf(-x));
    }
}

// ---------------------------------------------------------------------------
extern "C" void kernel_launch(void* const* d_in, const int* in_sizes, int n_in,
                              void* d_out, int out_size, void* d_ws, size_t ws_size,
                              hipStream_t stream) {
    const float* x_dense = (const float*)d_in[0];   // [4096,512]
    const float* tables  = (const float*)d_in[1];   // [4,500000,128]
    const float* bw0 = (const float*)d_in[2];
    const float* bb0 = (const float*)d_in[3];
    const float* bw1 = (const float*)d_in[4];
    const float* bb1 = (const float*)d_in[5];
    const float* bw2 = (const float*)d_in[6];
    const float* bb2 = (const float*)d_in[7];
    const float* tw0 = (const float*)d_in[8];
    const float* tb0 = (const float*)d_in[9];
    const float* tw1 = (const float*)d_in[10];
    const float* tb1 = (const float*)d_in[11];
    const float* tw2 = (const float*)d_in[12];
    const float* tb2 = (const float*)d_in[13];
    const int*   x_idx = (const int*)d_in[14];
    float* out = (float*)d_out;

    char* p = (char*)d_ws;
    auto alloc = [&](size_t bytes) {
        char* r = p; p += (bytes + 255) & ~(size_t)255; return r;
    };
    _Float16* xh   = (_Float16*)alloc((size_t)4096 * 512 * 2);
    _Float16* bw0h = (_Float16*)alloc((size_t)1024 * 512 * 2);
    _Float16* bw1h = (_Float16*)alloc((size_t)512 * 1024 * 2);
    _Float16* bw2h = (_Float16*)alloc((size_t)128 * 512 * 2);
    _Float16* tw0h = (_Float16*)alloc((size_t)1024 * 640 * 2);
    _Float16* tw1h = (_Float16*)alloc((size_t)512 * 1024 * 2);
    _Float16* tw2h = (_Float16*)alloc((size_t)512 * 2);
    _Float16* h0h  = (_Float16*)alloc((size_t)4096 * 1024 * 2);
    _Float16* h1h  = (_Float16*)alloc((size_t)4096 * 512 * 2);
    _Float16* feat = (_Float16*)alloc((size_t)4096 * 640 * 2);
    _Float16* z0h  = (_Float16*)alloc((size_t)4096 * 1024 * 2);
    _Float16* z1h  = (_Float16*)alloc((size_t)4096 * 512 * 2);

    CvtRest cr;
    cr.src[0] = bw1; cr.dst[0] = bw1h; cr.n4[0] = 512 * 1024 / 4;
    cr.src[1] = bw2; cr.dst[1] = bw2h; cr.n4[1] = 128 * 512 / 4;
    cr.src[2] = tw0; cr.dst[2] = tw0h; cr.n4[2] = 1024 * 640 / 4;
    cr.src[3] = tw1; cr.dst[3] = tw1h; cr.n4[3] = 512 * 1024 / 4;
    cr.src[4] = tw2; cr.dst[4] = tw2h; cr.n4[4] = 512 / 4;

    CvtRest cr0 = {};   // empty for D2/D3
    for (int i = 0; i < 5; ++i) { cr0.src[i] = bw1; cr0.dst[i] = bw1h; cr0.n4[i] = 0; }

    dim3 blk(256);

    // D0: cvt xh + bw0h (needed by D1's gemm1)
    cvt2_kernel<<<dim3(128), blk, 0, stream>>>(
        x_dense, xh, 4096 * 512 / 4, bw0, bw0h, 1024 * 512 / 4);

    // D1: gemm1 (256 blocks, 128x128) + cvt-rest (64) + emb bags [0,2048)
    fused_gemm_emb<128, 128, true><<<dim3(256 + 64 + 2048), blk, 0, stream>>>(
        xh, 512, bw0h, 512, bb0, h0h, 1024, 512,
        256, 32, 64, cr, 0, tables, x_idx, feat);

    // D2: gemm2 (128 blocks) + emb bags [2048,3328)
    fused_gemm_emb<128, 128, true><<<dim3(128 + 1280), blk, 0, stream>>>(
        h0h, 1024, bw1h, 1024, bb1, h1h, 512, 1024,
        128, 32, 0, cr0, 2048, tables, x_idx, feat);

    // D3: gemm3 (32 blocks, writes feat[:,0:128]) + emb bags [3328,4096)
    fused_gemm_emb<128, 128, true><<<dim3(32 + 768), blk, 0, stream>>>(
        h1h, 512, bw2h, 512, bb2, feat, 640, 512,
        32, 32, 0, cr0, 3328, tables, x_idx, feat);

    // D4: feat @ tw0^T -> z0 [4096,1024]
    gemm_h<128, 128, true><<<dim3(8, 32), blk, 0, stream>>>(
        feat, 640, tw0h, 640, tb0, z0h, 1024, 640);

    // D5: z0 @ tw1^T -> z1 [4096,512]
    gemm_h<128, 128, true><<<dim3(4, 32), blk, 0, stream>>>(
        z0h, 1024, tw1h, 1024, tb1, z1h, 512, 1024);

    // D6: sigmoid(z1 . tw2 + tb2)
    top2_h<<<dim3(1024), blk, 0, stream>>>(z1h, tw2h, tb2, out);
}